// Round 15
// baseline (159.785 us; speedup 1.0000x reference)
//
#include <hip/hip_runtime.h>
#include <cstdint>

// ---------------------------------------------------------------------------
// CTC loss pipeline (R12 base; single change: k_gemm 256x256 tile):
//   k_prep : x fp32->bf16, W[D,V] -> Wt[V,D] bf16, zero d_out
//   k_gemm : 256x256 tile, 8 waves, BK=64, double-buffered LDS (128 KB),
//            grid = 256 blocks = 1/CU. R13/R14 evidence: GEMM is bound by the
//            per-CU L1/TA staging port (~10.6 B/cy, tier-independent); staged
//            bytes scale as (1/BM+1/BN) -> 256^2 halves 268 MB -> 134 MB.
//            K-order/fragment math identical to R12 -> C bitwise identical.
//   k_softmax_gather : row lse + ext-label exp-gather -> pext (R12 exact)
//   k_ctc  : R12's passing producer/consumer (NPROD=6, NSLOT=4, 8-row chunks)
// ---------------------------------------------------------------------------

#define PROW 256                      // pext row: 256 floats = 1 KiB
#define PEXT_PAD_ROWS 64              // prefetch overrun pad (loaded, never consumed)
#define NPROD 6                       // producer waves
#define NSLOT 4                       // LDS ring slots (8 KiB each)
#define L2E 1.4426950408889634f
#define LN2 0.6931471805599453f

typedef short v8s __attribute__((ext_vector_type(8)));
typedef float v4f __attribute__((ext_vector_type(4)));

__device__ __forceinline__ uint32_t f2bf_bits(float f) {
  uint32_t u = __float_as_uint(f);
  return (u + 0x7FFFu + ((u >> 16) & 1u)) >> 16;   // RNE
}
__device__ __forceinline__ float bf2f(uint32_t h) { return __uint_as_float(h << 16); }

// ---------------- k_prep: x fp32->bf16, W transpose->bf16, zero d_out ----------------
__global__ void k_prep(const float* __restrict__ x, uint16_t* __restrict__ xb, long long n,
                       const float* __restrict__ W, uint16_t* __restrict__ Wt, int D, int V,
                       float* __restrict__ out, int nconv) {
  if (blockIdx.x == 0 && threadIdx.x == 0) out[0] = 0.f;   // zero the atomic target
  if ((int)blockIdx.x < nconv) {
    long long i = ((long long)blockIdx.x * blockDim.x + threadIdx.x) * 8;
    if (i >= n) return;
    float4 a = *(const float4*)(x + i);
    float4 b = *(const float4*)(x + i + 4);
    uint4 o;
    o.x = f2bf_bits(a.x) | (f2bf_bits(a.y) << 16);
    o.y = f2bf_bits(a.z) | (f2bf_bits(a.w) << 16);
    o.z = f2bf_bits(b.x) | (f2bf_bits(b.y) << 16);
    o.w = f2bf_bits(b.z) | (f2bf_bits(b.w) << 16);
    *(uint4*)(xb + i) = o;
  } else {
    __shared__ float tile[32][33];
    const int bid2 = blockIdx.x - nconv;
    const int n0 = (bid2 % (V / 32)) * 32, k0 = (bid2 / (V / 32)) * 32;
    const int tx = threadIdx.x & 31, ty = threadIdx.x >> 5;   // (32,8)
    #pragma unroll
    for (int i = 0; i < 32; i += 8)
      tile[ty + i][tx] = W[(size_t)(k0 + ty + i) * V + n0 + tx];
    __syncthreads();
    #pragma unroll
    for (int i = 0; i < 32; i += 8)
      Wt[(size_t)(n0 + ty + i) * D + k0 + tx] = (uint16_t)f2bf_bits(tile[tx][ty + i]);
  }
}

// ---------------- k_gemm: 256x256 tile, 8 waves, BK=64, double-buffered ----------------
// A:[M,K] bf16, Bt:[N,K] bf16 (=W^T). Per-wave output 128x64 (wm=wave&1 row
// half, wn=wave>>1 col quarter). LDS tiles [256][64] u16, linear rows (64B
// rows x2): gload_lds dest = wave-uniform base + lane*16B covers 8 rows/op.
__global__ __launch_bounds__(512) void k_gemm(const uint16_t* __restrict__ A,
                                              const uint16_t* __restrict__ Bt,
                                              const float* __restrict__ bias,
                                              uint16_t* __restrict__ C, int M, int N, int K) {
  __shared__ uint16_t As[2][256 * 64];   // 2 x 32 KB
  __shared__ uint16_t Bs[2][256 * 64];   // 2 x 32 KB
  const int tid = threadIdx.x, lane = tid & 63, wave = tid >> 6;
  int d = blockIdx.x;
  const int nwg = gridDim.x;
  if ((nwg & 7) == 0) d = (d & 7) * (nwg >> 3) + (d >> 3);
  const int ntl = N >> 8;                       // N-tiles of 256 (n-major)
  const int m0 = (d / ntl) * 256, n0 = (d % ntl) * 256;
  const int wm = wave & 1, wn = wave >> 1;      // row half / col quarter
  const int frow = lane & 15, kb = lane >> 4;
  const int slr = lane >> 3, skc = (lane & 7) * 8;   // staging: row-in-8 / k-chunk
  v4f acc[8][4] = {};

  #define GSTAGE(buf, kk) {                                                   \
    _Pragma("unroll")                                                         \
    for (int o = 0; o < 4; o++) {                                             \
      const int r0 = wave * 32 + o * 8;                                       \
      const uint16_t* ga = A + (size_t)(m0 + r0 + slr) * K + (kk) + skc;      \
      const uint16_t* gb = Bt + (size_t)(n0 + r0 + slr) * K + (kk) + skc;     \
      __builtin_amdgcn_global_load_lds(                                       \
          (const __attribute__((address_space(1))) void*)ga,                  \
          (__attribute__((address_space(3))) void*)(&As[buf][0] + r0 * 64 + lane * 8), 16, 0, 0); \
      __builtin_amdgcn_global_load_lds(                                       \
          (const __attribute__((address_space(1))) void*)gb,                  \
          (__attribute__((address_space(3))) void*)(&Bs[buf][0] + r0 * 64 + lane * 8), 16, 0, 0); \
    } }

  GSTAGE(0, 0);
  __syncthreads();                     // drain prologue stage (vmcnt(0)+barrier)
  int cur = 0;
  for (int k0 = 0; k0 < K; k0 += 64) {
    if (k0 + 64 < K) GSTAGE(cur ^ 1, k0 + 64);   // next tile in flight over compute
    #pragma unroll
    for (int t = 0; t < 2; t++) {
      v8s af[8], bf[4];
      #pragma unroll
      for (int i = 0; i < 8; i++)
        af[i] = *(const v8s*)(&As[cur][0] + (wm * 128 + i * 16 + frow) * 64 + t * 32 + kb * 8);
      #pragma unroll
      for (int j = 0; j < 4; j++)
        bf[j] = *(const v8s*)(&Bs[cur][0] + (wn * 64 + j * 16 + frow) * 64 + t * 32 + kb * 8);
      #pragma unroll
      for (int i = 0; i < 8; i++)
        #pragma unroll
        for (int j = 0; j < 4; j++)
          acc[i][j] = __builtin_amdgcn_mfma_f32_16x16x32_bf16(af[i], bf[j], acc[i][j], 0, 0, 0);
    }
    __syncthreads();                   // buf[cur] free to restage; buf[cur^1] ready
    cur ^= 1;
  }

  // epilogue: C/D layout col=lane&15, row=(lane>>4)*4+reg  [m89-verified]
  const int crow = (lane >> 4) * 4, ccol = lane & 15;
  #pragma unroll
  for (int j = 0; j < 4; j++) {
    const int n = n0 + wn * 64 + j * 16 + ccol;
    const float bv = bias[n];
    #pragma unroll
    for (int i = 0; i < 8; i++) {
      const int mb = m0 + wm * 128 + i * 16 + crow;
      #pragma unroll
      for (int r2 = 0; r2 < 4; r2++)
        C[(size_t)(mb + r2) * N + n] = (uint16_t)f2bf_bits(acc[i][j][r2] + bv);
    }
  }
}

// ---------------- k_softmax_gather: row lse + gather (linear domain) ----------------
__global__ void k_softmax_gather(const uint16_t* __restrict__ logits, const int* __restrict__ target,
                                 const int* __restrict__ tlen, float* __restrict__ pext,
                                 int T, int V, int L) {
  const int row = blockIdx.x * 4 + (threadIdx.x >> 6);   // one wave per row
  const int lane = threadIdx.x & 63;
  const uint16_t* lrow = logits + (size_t)row * V;

  float xs[16];
  int cnt = 0;
  float mx = -INFINITY;
  for (int base = 0; base < V; base += 256) {
    const int idx = base + lane * 4;
    uint2 u = *(const uint2*)(lrow + idx);
    float4 v;
    v.x = bf2f(u.x & 0xFFFFu); v.y = bf2f(u.x >> 16);
    v.z = bf2f(u.y & 0xFFFFu); v.w = bf2f(u.y >> 16);
    xs[cnt] = v.x; xs[cnt + 1] = v.y; xs[cnt + 2] = v.z; xs[cnt + 3] = v.w; cnt += 4;
    mx = fmaxf(mx, fmaxf(fmaxf(v.x, v.y), fmaxf(v.z, v.w)));
  }
  #pragma unroll
  for (int off = 32; off; off >>= 1) mx = fmaxf(mx, __shfl_xor(mx, off, 64));
  float sum = 0.f;
  #pragma unroll
  for (int q = 0; q < 16; q++) { if (q < cnt) sum += exp2f((xs[q] - mx) * L2E); }
  #pragma unroll
  for (int off = 32; off; off >>= 1) sum += __shfl_xor(sum, off, 64);
  const float lse2 = mx * L2E + log2f(sum);

  const int bidx = row / T;
  const int Lb = tlen[bidx];
  const int S = 2 * Lb + 1;
  float* prow = pext + (size_t)row * PROW;
  #pragma unroll
  for (int it = 0; it < PROW / 64; it++) {
    const int s = lane + it * 64;
    float p = 0.f;
    if (s < S) {
      const int lbl = (s & 1) ? target[bidx * L + ((s - 1) >> 1)] : 0;
      p = exp2f(bf2f(lrow[lbl]) * L2E - lse2);
    }
    prow[s] = p;
  }
}

// ---------------- k_ctc: producer/consumer (R12-passing) ----------------
__device__ __forceinline__ float wave_shr1(float x) {   // lane l <- lane l-1, lane0 <- 0
  return __int_as_float(__builtin_amdgcn_update_dpp(0, __float_as_int(x), 0x138, 0xf, 0xf, true));
}
__device__ __forceinline__ float wave_max_nonneg(float x) {
  x = fmaxf(x, __int_as_float(__builtin_amdgcn_update_dpp(0, __float_as_int(x), 0x111, 0xf, 0xf, true)));
  x = fmaxf(x, __int_as_float(__builtin_amdgcn_update_dpp(0, __float_as_int(x), 0x112, 0xf, 0xf, true)));
  x = fmaxf(x, __int_as_float(__builtin_amdgcn_update_dpp(0, __float_as_int(x), 0x114, 0xf, 0xf, true)));
  x = fmaxf(x, __int_as_float(__builtin_amdgcn_update_dpp(0, __float_as_int(x), 0x118, 0xf, 0xf, true)));
  x = fmaxf(x, __int_as_float(__builtin_amdgcn_update_dpp(0, __float_as_int(x), 0x142, 0xf, 0xf, true)));
  x = fmaxf(x, __int_as_float(__builtin_amdgcn_update_dpp(0, __float_as_int(x), 0x143, 0xf, 0xf, true)));
  return __int_as_float(__builtin_amdgcn_readlane(__float_as_int(x), 63));
}

__global__ __launch_bounds__(448, 1) void k_ctc(const float* __restrict__ pext,
                                                const int* __restrict__ target,
                                                const int* __restrict__ ilen,
                                                const int* __restrict__ tlen,
                                                float* __restrict__ out, int T, int L) {
  __shared__ __attribute__((aligned(16))) float ring[NSLOT][8][PROW];   // 32 KiB
  __shared__ float abuf[257];

  const int b = blockIdx.x;
  const int tid = threadIdx.x;
  const int lane = tid & 63, wave = tid >> 6;
  const int B = gridDim.x;
  const int Tb = ilen[b];
  const int Lb = tlen[b];
  const int S = 2 * Lb + 1;
  const int* tg = target + b * L;
  const float* pb = pext + (size_t)b * T * PROW;
  const int CT = (Tb - 1) / 8 + 1;   // every wave: CT+1 s_barriers

  if (wave > 0) {
    // ---------------- producers (waves 1..NPROD) ----------------
    const int p = wave - 1;              // owns chunks c with c % NPROD == p
    float4 P0, P1, P2, P3, P4, P5, P6, P7;   // named regs: no spill (R5 lesson)

    #define LOADCHUNK(c) {                                                  \
      const float* s_ = pb + (size_t)(1 + 8 * (c)) * PROW + (lane << 2);    \
      P0 = *(const float4*)(s_);            P1 = *(const float4*)(s_ + PROW);     \
      P2 = *(const float4*)(s_ + 2 * PROW); P3 = *(const float4*)(s_ + 3 * PROW); \
      P4 = *(const float4*)(s_ + 4 * PROW); P5 = *(const float4*)(s_ + 5 * PROW); \
      P6 = *(const float4*)(s_ + 6 * PROW); P7 = *(const float4*)(s_ + 7 * PROW); }
    #define WRITECHUNK(c) {                                                 \
      const int sl_ = (c) & (NSLOT - 1);                                    \
      *(float4*)(&ring[sl_][0][lane << 2]) = P0; *(float4*)(&ring[sl_][1][lane << 2]) = P1; \
      *(float4*)(&ring[sl_][2][lane << 2]) = P2; *(float4*)(&ring[sl_][3][lane << 2]) = P3; \
      *(float4*)(&ring[sl_][4][lane << 2]) = P4; *(float4*)(&ring[sl_][5][lane << 2]) = P5; \
      *(float4*)(&ring[sl_][6][lane << 2]) = P6; *(float4*)(&ring[sl_][7][lane << 2]) = P7; }

    if (p < CT) LOADCHUNK(p);            // first owned chunk
    if (p == 0 && 0 < CT) {              // publish chunk 0 in the prologue
      WRITECHUNK(0);
      asm volatile("s_waitcnt lgkmcnt(0)" ::: "memory");   // drain publish first
      if (NPROD < CT) LOADCHUNK(NPROD);  // in flight across barriers
      __builtin_amdgcn_sched_barrier(0);
    }
    __builtin_amdgcn_s_barrier();        // prologue barrier

    for (int c = 0; c < CT; ++c) {
      const int cpub = c + 1;            // chunk consumed at phase c+1
      if (cpub < CT && (cpub % NPROD) == p) {
        WRITECHUNK(cpub);                // regs loaded NPROD phases ago
        asm volatile("s_waitcnt lgkmcnt(0)" ::: "memory");
        const int cn = cpub + NPROD;
        if (cn < CT) LOADCHUNK(cn);
        __builtin_amdgcn_sched_barrier(0);
      }
      __builtin_amdgcn_s_barrier();
    }
    return;
  }

  // ---------------- wave 0: consumer (bit-identical arithmetic to R4/R8/R12) ----------------
  const int s1 = 4 * lane + 1, s3 = 4 * lane + 3;
  float sk1 = 0.f, sk3 = 0.f;
  if (s1 >= 3 && s1 < S) sk1 = (tg[(s1 - 1) >> 1] != tg[(s1 - 3) >> 1]) ? 1.f : 0.f;
  if (s3 >= 3 && s3 < S) sk3 = (tg[(s3 - 1) >> 1] != tg[(s3 - 3) >> 1]) ? 1.f : 0.f;

  const float4 p0 = *(const float4*)(pb + (lane << 2));
  float a0 = (lane == 0) ? p0.x : 0.f;
  float a1 = (lane == 0) ? p0.y : 0.f;
  float a2 = 0.f, a3 = 0.f, a4 = 0.f;
  float log2C = 0.f;

  // State 256 is even -> blank -> equals prow[0] (lane 0's P.x): readlane.
  #define CTC_STEP(PP) {                                                \
    const float pm3 = wave_shr1(a3);                                    \
    const float a255 = __int_as_float(__builtin_amdgcn_readlane(__float_as_int(a3), 63)); \
    const float p4v = __int_as_float(__builtin_amdgcn_readlane(__float_as_int((PP).x), 0)); \
    const float n0v = (a0 + pm3) * (PP).x;                              \
    const float n1v = (a1 + a0 + sk1 * pm3) * (PP).y;                   \
    const float n2v = (a2 + a1) * (PP).z;                               \
    const float n3v = (a3 + a2 + sk3 * a1) * (PP).w;                    \
    const float n4v = (a4 + a255) * p4v;                                \
    a0 = n0v; a1 = n1v; a2 = n2v; a3 = n3v; a4 = n4v; }

  #define RENORM {                                                      \
    float m = fmaxf(fmaxf(fmaxf(a0, a1), fmaxf(a2, a3)), a4);           \
    m = wave_max_nonneg(m);                                             \
    const int e = (int)((__float_as_uint(m) >> 23) & 255u) - 127;       \
    const float scale = __uint_as_float((uint32_t)(127 - e) << 23);     \
    a0 *= scale; a1 *= scale; a2 *= scale; a3 *= scale; a4 *= scale;    \
    log2C += (float)e; }

  __builtin_amdgcn_s_barrier();          // prologue barrier (chunk 0 published)

  for (int c = 0; c < CT; ++c) {
    const int slot = c & (NSLOT - 1);
    float4 P[8];
    #pragma unroll
    for (int k = 0; k < 8; ++k)
      P[k] = *(const float4*)(&ring[slot][k][lane << 2]);
    const int t0 = 1 + 8 * c;
    if (t0 + 8 <= Tb) {
      #pragma unroll
      for (int k = 0; k < 8; ++k) CTC_STEP(P[k]);
      RENORM;
    } else {
      #pragma unroll
      for (int k = 0; k < 8; ++k) { if (t0 + k < Tb) CTC_STEP(P[k]); }
      RENORM;
    }
    __builtin_amdgcn_s_barrier();
  }

  abuf[4 * lane + 0] = a0; abuf[4 * lane + 1] = a1;
  abuf[4 * lane + 2] = a2; abuf[4 * lane + 3] = a3;
  if (lane == 63) abuf[256] = a4;
  // abuf is written and read by wave 0 only (in-wave DS ordering suffices).
  if (lane == 0) {
    const float ssum = abuf[2 * Lb - 1] + abuf[2 * Lb];
    const float ll = (log2f(ssum) + log2C) * LN2;
    float nll = -ll;
    if (!(nll < 1e29f)) nll = 0.f;                 // zero_infinity (also catches inf/nan)
    atomicAdd(out, nll / ((float)(Lb > 0 ? Lb : 1) * (float)B));
  }
}

// ---------------------------------------------------------------------------
extern "C" void kernel_launch(void* const* d_in, const int* in_sizes, int n_in,
                              void* d_out, int out_size, void* d_ws, size_t ws_size,
                              hipStream_t stream) {
  const float* x      = (const float*)d_in[0];
  const float* W      = (const float*)d_in[1];
  const float* bias   = (const float*)d_in[2];
  const int*  target  = (const int*)d_in[3];
  const int*  ilen    = (const int*)d_in[4];
  const int*  tlen    = (const int*)d_in[5];

  const int B = in_sizes[4];
  const int V = in_sizes[2];
  const int D = in_sizes[1] / V;
  const int T = in_sizes[0] / (B * D);
  const int L = in_sizes[3] / B;
  const int M = B * T;

  char* ws = (char*)d_ws;
  const size_t xb_bytes = (size_t)M * D * 2;
  const size_t wt_bytes = (size_t)V * D * 2;
  uint16_t* xb = (uint16_t*)ws;
  uint16_t* Wt = (uint16_t*)(ws + xb_bytes);
  uint16_t* logits = (uint16_t*)(ws + xb_bytes + wt_bytes);
  const size_t log_bytes = (size_t)M * V * 2;

  const size_t pext_bytes = (size_t)(M + PEXT_PAD_ROWS) * PROW * 4;
  float* pext;
  if (pext_bytes <= xb_bytes + wt_bytes) {
    pext = (float*)ws;                 // overlay dead xb/Wt region after GEMM
  } else {
    pext = (float*)(ws + xb_bytes + wt_bytes + log_bytes);
  }

  const long long nx = (long long)M * D;
  const int nconv = (int)((nx / 8 + 255) / 256);
  const int ntrans = (V / 32) * (D / 32);
  k_prep<<<nconv + ntrans, 256, 0, stream>>>(x, xb, nx, W, Wt, D, V, (float*)d_out, nconv);
  k_gemm<<<(M / 256) * (V / 256), 512, 0, stream>>>(xb, Wt, bias, logits, M, V, D);
  k_softmax_gather<<<M / 4, 256, 0, stream>>>(logits, target, tlen, pext, T, V, L);
  k_ctc<<<B, 64 * (1 + NPROD), 0, stream>>>(pext, target, ilen, tlen, (float*)d_out, T, L);
}

// Round 16
// 154.641 us; speedup vs baseline: 1.0333x; 1.0333x over previous
//
#include <hip/hip_runtime.h>
#include <cstdint>

// ---------------------------------------------------------------------------
// CTC loss pipeline (R12 best-passing base; single tweak: softmax uint4 loads):
//   k_prep : x fp32->bf16, W[D,V] -> Wt[V,D] bf16, zero d_out
//   k_gemm : m97-structure bf16 MFMA GEMM, BK=64, 1-D grid with chunked-XCD
//            swizzle (n-major). 128x128 (R14 dbuf neutral, R15 256^2 worse).
//   k_softmax_gather : row lse + ext-label exp-gather -> pext. TWEAK: 16B/lane
//            loads (uint4), 2 sweep iters instead of 4 (per-wave port-bound).
//   k_ctc  : R12's passing producer/consumer (NPROD=6, NSLOT=4, 8-row chunks,
//            drain-then-reload publish). ~1000cy/phase = consumer's intrinsic
//            serial chain (5 structures converged here).
// ---------------------------------------------------------------------------

#define PROW 256                      // pext row: 256 floats = 1 KiB
#define PEXT_PAD_ROWS 64              // prefetch overrun pad (loaded, never consumed)
#define NPROD 6                       // producer waves
#define NSLOT 4                       // LDS ring slots (8 KiB each)
#define L2E 1.4426950408889634f
#define LN2 0.6931471805599453f

typedef short v8s __attribute__((ext_vector_type(8)));
typedef float v4f __attribute__((ext_vector_type(4)));

__device__ __forceinline__ uint32_t f2bf_bits(float f) {
  uint32_t u = __float_as_uint(f);
  return (u + 0x7FFFu + ((u >> 16) & 1u)) >> 16;   // RNE
}
__device__ __forceinline__ float bf2f(uint32_t h) { return __uint_as_float(h << 16); }

// ---------------- k_prep: x fp32->bf16, W transpose->bf16, zero d_out ----------------
__global__ void k_prep(const float* __restrict__ x, uint16_t* __restrict__ xb, long long n,
                       const float* __restrict__ W, uint16_t* __restrict__ Wt, int D, int V,
                       float* __restrict__ out, int nconv) {
  if (blockIdx.x == 0 && threadIdx.x == 0) out[0] = 0.f;   // zero the atomic target
  if ((int)blockIdx.x < nconv) {
    long long i = ((long long)blockIdx.x * blockDim.x + threadIdx.x) * 8;
    if (i >= n) return;
    float4 a = *(const float4*)(x + i);
    float4 b = *(const float4*)(x + i + 4);
    uint4 o;
    o.x = f2bf_bits(a.x) | (f2bf_bits(a.y) << 16);
    o.y = f2bf_bits(a.z) | (f2bf_bits(a.w) << 16);
    o.z = f2bf_bits(b.x) | (f2bf_bits(b.y) << 16);
    o.w = f2bf_bits(b.z) | (f2bf_bits(b.w) << 16);
    *(uint4*)(xb + i) = o;
  } else {
    __shared__ float tile[32][33];
    const int bid2 = blockIdx.x - nconv;
    const int n0 = (bid2 % (V / 32)) * 32, k0 = (bid2 / (V / 32)) * 32;
    const int tx = threadIdx.x & 31, ty = threadIdx.x >> 5;   // (32,8)
    #pragma unroll
    for (int i = 0; i < 32; i += 8)
      tile[ty + i][tx] = W[(size_t)(k0 + ty + i) * V + n0 + tx];
    __syncthreads();
    #pragma unroll
    for (int i = 0; i < 32; i += 8)
      Wt[(size_t)(n0 + ty + i) * D + k0 + tx] = (uint16_t)f2bf_bits(tile[tx][ty + i]);
  }
}

// ---------------- k_gemm: m97 structure, BK=64, bf16 out, 1-D swizzled grid ----------------
__global__ __launch_bounds__(256) void k_gemm(const uint16_t* __restrict__ A,
                                              const uint16_t* __restrict__ Bt,
                                              const float* __restrict__ bias,
                                              uint16_t* __restrict__ C, int M, int N, int K) {
  __shared__ uint16_t As[2][128 * 32];   // [k-half][row*32 + k]  (64B rows)
  __shared__ uint16_t Bs[2][128 * 32];
  const int tid = threadIdx.x, lane = tid & 63, wave = tid >> 6;
  int d = blockIdx.x;
  const int nwg = gridDim.x;
  if ((nwg & 7) == 0) d = (d & 7) * (nwg >> 3) + (d >> 3);
  const int ntl = N >> 7;                       // N-tiles (n-major: fastest)
  const int m0 = (d / ntl) * 128, n0 = (d % ntl) * 128;
  const int wm = wave & 1, wn = wave >> 1;
  const int frow = lane & 15, kb = lane >> 4;
  const int lr = lane >> 2, kc = lane & 3;
  v4f acc[4][4] = {};

  for (int k0 = 0; k0 < K; k0 += 64) {
    __syncthreads();
    #pragma unroll
    for (int t = 0; t < 2; t++)
      #pragma unroll
      for (int i = 0; i < 2; i++) {
        const int r = (wave * 2 + i) * 16 + lr;
        const uint16_t* ga = A + (size_t)(m0 + r) * K + k0 + t * 32 + kc * 8;
        const uint16_t* gb = Bt + (size_t)(n0 + r) * K + k0 + t * 32 + kc * 8;
        __builtin_amdgcn_global_load_lds(
            (const __attribute__((address_space(1))) void*)ga,
            (__attribute__((address_space(3))) void*)(&As[t][0] + (wave * 2 + i) * 512 + lane * 8), 16, 0, 0);
        __builtin_amdgcn_global_load_lds(
            (const __attribute__((address_space(1))) void*)gb,
            (__attribute__((address_space(3))) void*)(&Bs[t][0] + (wave * 2 + i) * 512 + lane * 8), 16, 0, 0);
      }
    __syncthreads();

    #pragma unroll
    for (int t = 0; t < 2; t++) {
      v8s af[4], bf[4];
      #pragma unroll
      for (int i = 0; i < 4; i++)
        af[i] = *(const v8s*)(&As[t][0] + (wm * 64 + i * 16 + frow) * 32 + kb * 8);
      #pragma unroll
      for (int j = 0; j < 4; j++)
        bf[j] = *(const v8s*)(&Bs[t][0] + (wn * 64 + j * 16 + frow) * 32 + kb * 8);
      #pragma unroll
      for (int i = 0; i < 4; i++)
        #pragma unroll
        for (int j = 0; j < 4; j++)
          acc[i][j] = __builtin_amdgcn_mfma_f32_16x16x32_bf16(af[i], bf[j], acc[i][j], 0, 0, 0);
    }
  }

  // epilogue: C/D layout col=lane&15, row=(lane>>4)*4+reg  [m89-verified]
  const int crow = (lane >> 4) * 4, ccol = lane & 15;
  #pragma unroll
  for (int j = 0; j < 4; j++) {
    const int n = n0 + wn * 64 + j * 16 + ccol;
    const float bv = bias[n];
    #pragma unroll
    for (int i = 0; i < 4; i++) {
      const int mb = m0 + wm * 64 + i * 16 + crow;
      #pragma unroll
      for (int r2 = 0; r2 < 4; r2++)
        C[(size_t)(mb + r2) * N + n] = (uint16_t)f2bf_bits(acc[i][j][r2] + bv);
    }
  }
}

// ---------------- k_softmax_gather: row lse + gather (linear domain) ----------------
__global__ void k_softmax_gather(const uint16_t* __restrict__ logits, const int* __restrict__ target,
                                 const int* __restrict__ tlen, float* __restrict__ pext,
                                 int T, int V, int L) {
  const int row = blockIdx.x * 4 + (threadIdx.x >> 6);   // one wave per row
  const int lane = threadIdx.x & 63;
  const uint16_t* lrow = logits + (size_t)row * V;

  float xs[16];
  int cnt = 0;
  float mx = -INFINITY;
  for (int base = 0; base < V; base += 512) {            // 16B/lane: 2 iters
    const int idx = base + lane * 8;
    uint4 u = *(const uint4*)(lrow + idx);
    float v0 = bf2f(u.x & 0xFFFFu), v1 = bf2f(u.x >> 16);
    float v2 = bf2f(u.y & 0xFFFFu), v3 = bf2f(u.y >> 16);
    float v4 = bf2f(u.z & 0xFFFFu), v5 = bf2f(u.z >> 16);
    float v6 = bf2f(u.w & 0xFFFFu), v7 = bf2f(u.w >> 16);
    xs[cnt] = v0; xs[cnt + 1] = v1; xs[cnt + 2] = v2; xs[cnt + 3] = v3;
    xs[cnt + 4] = v4; xs[cnt + 5] = v5; xs[cnt + 6] = v6; xs[cnt + 7] = v7; cnt += 8;
    mx = fmaxf(mx, fmaxf(fmaxf(fmaxf(v0, v1), fmaxf(v2, v3)),
                         fmaxf(fmaxf(v4, v5), fmaxf(v6, v7))));
  }
  #pragma unroll
  for (int off = 32; off; off >>= 1) mx = fmaxf(mx, __shfl_xor(mx, off, 64));
  float sum = 0.f;
  #pragma unroll
  for (int q = 0; q < 16; q++) { if (q < cnt) sum += exp2f((xs[q] - mx) * L2E); }
  #pragma unroll
  for (int off = 32; off; off >>= 1) sum += __shfl_xor(sum, off, 64);
  const float lse2 = mx * L2E + log2f(sum);

  const int bidx = row / T;
  const int Lb = tlen[bidx];
  const int S = 2 * Lb + 1;
  float* prow = pext + (size_t)row * PROW;
  #pragma unroll
  for (int it = 0; it < PROW / 64; it++) {
    const int s = lane + it * 64;
    float p = 0.f;
    if (s < S) {
      const int lbl = (s & 1) ? target[bidx * L + ((s - 1) >> 1)] : 0;
      p = exp2f(bf2f(lrow[lbl]) * L2E - lse2);
    }
    prow[s] = p;
  }
}

// ---------------- k_ctc: producer/consumer (R12-passing, drain-then-reload) ----------------
__device__ __forceinline__ float wave_shr1(float x) {   // lane l <- lane l-1, lane0 <- 0
  return __int_as_float(__builtin_amdgcn_update_dpp(0, __float_as_int(x), 0x138, 0xf, 0xf, true));
}
__device__ __forceinline__ float wave_max_nonneg(float x) {
  x = fmaxf(x, __int_as_float(__builtin_amdgcn_update_dpp(0, __float_as_int(x), 0x111, 0xf, 0xf, true)));
  x = fmaxf(x, __int_as_float(__builtin_amdgcn_update_dpp(0, __float_as_int(x), 0x112, 0xf, 0xf, true)));
  x = fmaxf(x, __int_as_float(__builtin_amdgcn_update_dpp(0, __float_as_int(x), 0x114, 0xf, 0xf, true)));
  x = fmaxf(x, __int_as_float(__builtin_amdgcn_update_dpp(0, __float_as_int(x), 0x118, 0xf, 0xf, true)));
  x = fmaxf(x, __int_as_float(__builtin_amdgcn_update_dpp(0, __float_as_int(x), 0x142, 0xf, 0xf, true)));
  x = fmaxf(x, __int_as_float(__builtin_amdgcn_update_dpp(0, __float_as_int(x), 0x143, 0xf, 0xf, true)));
  return __int_as_float(__builtin_amdgcn_readlane(__float_as_int(x), 63));
}

__global__ __launch_bounds__(448, 1) void k_ctc(const float* __restrict__ pext,
                                                const int* __restrict__ target,
                                                const int* __restrict__ ilen,
                                                const int* __restrict__ tlen,
                                                float* __restrict__ out, int T, int L) {
  __shared__ __attribute__((aligned(16))) float ring[NSLOT][8][PROW];   // 32 KiB
  __shared__ float abuf[257];

  const int b = blockIdx.x;
  const int tid = threadIdx.x;
  const int lane = tid & 63, wave = tid >> 6;
  const int B = gridDim.x;
  const int Tb = ilen[b];
  const int Lb = tlen[b];
  const int S = 2 * Lb + 1;
  const int* tg = target + b * L;
  const float* pb = pext + (size_t)b * T * PROW;
  const int CT = (Tb - 1) / 8 + 1;   // every wave: CT+1 s_barriers

  if (wave > 0) {
    // ---------------- producers (waves 1..NPROD) ----------------
    const int p = wave - 1;              // owns chunks c with c % NPROD == p
    float4 P0, P1, P2, P3, P4, P5, P6, P7;   // named regs: no spill (R5 lesson)

    #define LOADCHUNK(c) {                                                  \
      const float* s_ = pb + (size_t)(1 + 8 * (c)) * PROW + (lane << 2);    \
      P0 = *(const float4*)(s_);            P1 = *(const float4*)(s_ + PROW);     \
      P2 = *(const float4*)(s_ + 2 * PROW); P3 = *(const float4*)(s_ + 3 * PROW); \
      P4 = *(const float4*)(s_ + 4 * PROW); P5 = *(const float4*)(s_ + 5 * PROW); \
      P6 = *(const float4*)(s_ + 6 * PROW); P7 = *(const float4*)(s_ + 7 * PROW); }
    #define WRITECHUNK(c) {                                                 \
      const int sl_ = (c) & (NSLOT - 1);                                    \
      *(float4*)(&ring[sl_][0][lane << 2]) = P0; *(float4*)(&ring[sl_][1][lane << 2]) = P1; \
      *(float4*)(&ring[sl_][2][lane << 2]) = P2; *(float4*)(&ring[sl_][3][lane << 2]) = P3; \
      *(float4*)(&ring[sl_][4][lane << 2]) = P4; *(float4*)(&ring[sl_][5][lane << 2]) = P5; \
      *(float4*)(&ring[sl_][6][lane << 2]) = P6; *(float4*)(&ring[sl_][7][lane << 2]) = P7; }

    if (p < CT) LOADCHUNK(p);            // first owned chunk
    if (p == 0 && 0 < CT) {              // publish chunk 0 in the prologue
      WRITECHUNK(0);
      asm volatile("s_waitcnt lgkmcnt(0)" ::: "memory");   // drain publish first
      if (NPROD < CT) LOADCHUNK(NPROD);  // in flight across barriers
      __builtin_amdgcn_sched_barrier(0);
    }
    __builtin_amdgcn_s_barrier();        // prologue barrier

    for (int c = 0; c < CT; ++c) {
      const int cpub = c + 1;            // chunk consumed at phase c+1
      if (cpub < CT && (cpub % NPROD) == p) {
        WRITECHUNK(cpub);                // regs loaded NPROD phases ago
        asm volatile("s_waitcnt lgkmcnt(0)" ::: "memory");
        const int cn = cpub + NPROD;
        if (cn < CT) LOADCHUNK(cn);
        __builtin_amdgcn_sched_barrier(0);
      }
      __builtin_amdgcn_s_barrier();
    }
    return;
  }

  // ---------------- wave 0: consumer (bit-identical arithmetic to R4/R8/R12) ----------------
  const int s1 = 4 * lane + 1, s3 = 4 * lane + 3;
  float sk1 = 0.f, sk3 = 0.f;
  if (s1 >= 3 && s1 < S) sk1 = (tg[(s1 - 1) >> 1] != tg[(s1 - 3) >> 1]) ? 1.f : 0.f;
  if (s3 >= 3 && s3 < S) sk3 = (tg[(s3 - 1) >> 1] != tg[(s3 - 3) >> 1]) ? 1.f : 0.f;

  const float4 p0 = *(const float4*)(pb + (lane << 2));
  float a0 = (lane == 0) ? p0.x : 0.f;
  float a1 = (lane == 0) ? p0.y : 0.f;
  float a2 = 0.f, a3 = 0.f, a4 = 0.f;
  float log2C = 0.f;

  // State 256 is even -> blank -> equals prow[0] (lane 0's P.x): readlane.
  #define CTC_STEP(PP) {                                                \
    const float pm3 = wave_shr1(a3);                                    \
    const float a255 = __int_as_float(__builtin_amdgcn_readlane(__float_as_int(a3), 63)); \
    const float p4v = __int_as_float(__builtin_amdgcn_readlane(__float_as_int((PP).x), 0)); \
    const float n0v = (a0 + pm3) * (PP).x;                              \
    const float n1v = (a1 + a0 + sk1 * pm3) * (PP).y;                   \
    const float n2v = (a2 + a1) * (PP).z;                               \
    const float n3v = (a3 + a2 + sk3 * a1) * (PP).w;                    \
    const float n4v = (a4 + a255) * p4v;                                \
    a0 = n0v; a1 = n1v; a2 = n2v; a3 = n3v; a4 = n4v; }

  #define RENORM {                                                      \
    float m = fmaxf(fmaxf(fmaxf(a0, a1), fmaxf(a2, a3)), a4);           \
    m = wave_max_nonneg(m);                                             \
    const int e = (int)((__float_as_uint(m) >> 23) & 255u) - 127;       \
    const float scale = __uint_as_float((uint32_t)(127 - e) << 23);     \
    a0 *= scale; a1 *= scale; a2 *= scale; a3 *= scale; a4 *= scale;    \
    log2C += (float)e; }

  __builtin_amdgcn_s_barrier();          // prologue barrier (chunk 0 published)

  for (int c = 0; c < CT; ++c) {
    const int slot = c & (NSLOT - 1);
    float4 P[8];
    #pragma unroll
    for (int k = 0; k < 8; ++k)
      P[k] = *(const float4*)(&ring[slot][k][lane << 2]);
    const int t0 = 1 + 8 * c;
    if (t0 + 8 <= Tb) {
      #pragma unroll
      for (int k = 0; k < 8; ++k) CTC_STEP(P[k]);
      RENORM;
    } else {
      #pragma unroll
      for (int k = 0; k < 8; ++k) { if (t0 + k < Tb) CTC_STEP(P[k]); }
      RENORM;
    }
    __builtin_amdgcn_s_barrier();
  }

  abuf[4 * lane + 0] = a0; abuf[4 * lane + 1] = a1;
  abuf[4 * lane + 2] = a2; abuf[4 * lane + 3] = a3;
  if (lane == 63) abuf[256] = a4;
  // abuf is written and read by wave 0 only (in-wave DS ordering suffices).
  if (lane == 0) {
    const float ssum = abuf[2 * Lb - 1] + abuf[2 * Lb];
    const float ll = (log2f(ssum) + log2C) * LN2;
    float nll = -ll;
    if (!(nll < 1e29f)) nll = 0.f;                 // zero_infinity (also catches inf/nan)
    atomicAdd(out, nll / ((float)(Lb > 0 ? Lb : 1) * (float)B));
  }
}

// ---------------------------------------------------------------------------
extern "C" void kernel_launch(void* const* d_in, const int* in_sizes, int n_in,
                              void* d_out, int out_size, void* d_ws, size_t ws_size,
                              hipStream_t stream) {
  const float* x      = (const float*)d_in[0];
  const float* W      = (const float*)d_in[1];
  const float* bias   = (const float*)d_in[2];
  const int*  target  = (const int*)d_in[3];
  const int*  ilen    = (const int*)d_in[4];
  const int*  tlen    = (const int*)d_in[5];

  const int B = in_sizes[4];
  const int V = in_sizes[2];
  const int D = in_sizes[1] / V;
  const int T = in_sizes[0] / (B * D);
  const int L = in_sizes[3] / B;
  const int M = B * T;

  char* ws = (char*)d_ws;
  const size_t xb_bytes = (size_t)M * D * 2;
  const size_t wt_bytes = (size_t)V * D * 2;
  uint16_t* xb = (uint16_t*)ws;
  uint16_t* Wt = (uint16_t*)(ws + xb_bytes);
  uint16_t* logits = (uint16_t*)(ws + xb_bytes + wt_bytes);
  const size_t log_bytes = (size_t)M * V * 2;

  const size_t pext_bytes = (size_t)(M + PEXT_PAD_ROWS) * PROW * 4;
  float* pext;
  if (pext_bytes <= xb_bytes + wt_bytes) {
    pext = (float*)ws;                 // overlay dead xb/Wt region after GEMM
  } else {
    pext = (float*)(ws + xb_bytes + wt_bytes + log_bytes);
  }

  const long long nx = (long long)M * D;
  const int nconv = (int)((nx / 8 + 255) / 256);
  const int ntrans = (V / 32) * (D / 32);
  k_prep<<<nconv + ntrans, 256, 0, stream>>>(x, xb, nx, W, Wt, D, V, (float*)d_out, nconv);
  k_gemm<<<(M / 128) * (V / 128), 256, 0, stream>>>(xb, Wt, bias, logits, M, V, D);
  k_softmax_gather<<<M / 4, 256, 0, stream>>>(logits, target, tlen, pext, T, V, L);
  k_ctc<<<B, 64 * (1 + NPROD), 0, stream>>>(pext, target, ilen, tlen, (float*)d_out, T, L);
}